// Round 13
// baseline (1817.387 us; speedup 1.0000x reference)
//
#include <hip/hip_runtime.h>

typedef unsigned short u16;
typedef unsigned int u32;
typedef __attribute__((ext_vector_type(8))) short short8;   // 8 bf16 (4 VGPRs)
typedef __attribute__((ext_vector_type(4))) float f32x4;    // MFMA acc

// ---------- bf16 helpers ----------
__device__ __forceinline__ float bf2f(unsigned v){ union{unsigned u; float f;} c; c.u = v<<16; return c.f; }
__device__ __forceinline__ u16 f2bf(float f){
  union{float f; unsigned u;} c; c.f=f;
  unsigned u = c.u;
  u += 0x7fffu + ((u>>16)&1u);
  return (u16)(u>>16);
}
__device__ __forceinline__ float bfLO(u32 x){ union{u32 u; float f;} c; c.u = x<<16;        return c.f; }
__device__ __forceinline__ float bfHI(u32 x){ union{u32 u; float f;} c; c.u = x&0xffff0000u; return c.f; }

#define GLDS(g, l) __builtin_amdgcn_global_load_lds( \
    (const __attribute__((address_space(1))) void*)(g), \
    (__attribute__((address_space(3))) void*)(l), 16, 0, 0)

// ---------- top-K=16 of each row of A (512x512), descending, stable ----------
__global__ void topk_kernel(const float* __restrict__ A, int* __restrict__ idx){
  __shared__ float vals[512];
  const int n = blockIdx.x, t = threadIdx.x; // 64 threads = 1 wave
  for(int i=t;i<512;i+=64) vals[i] = A[n*512+i];
  __syncthreads();
  for(int kk=0;kk<16;kk++){
    float bv = -1e30f; int bi = 1<<30;
    for(int i=t;i<512;i+=64){
      float v = vals[i];
      if(v > bv){ bv=v; bi=i; }
    }
    #pragma unroll
    for(int off=32; off>0; off>>=1){
      float ov = __shfl_down(bv, off);
      int   oi = __shfl_down(bi, off);
      if(ov > bv || (ov==bv && oi<bi)){ bv=ov; bi=oi; }
    }
    bi = __shfl(bi, 0);
    if(t==0){ idx[n*16+kk] = bi; vals[bi] = -1e30f; }
    __syncthreads();
  }
}

// ---------- transpose + f32->bf16: [R][C] -> [C][R] bf16, batched over z ----------
__global__ __launch_bounds__(256)
void tcvt_kernel(const float* __restrict__ src, u16* __restrict__ dst, int R, int C){
  __shared__ float t[32][33];
  const int m = blockIdx.z;
  src += (size_t)m*R*C; dst += (size_t)m*R*C;
  const int c0 = blockIdx.x*32, r0 = blockIdx.y*32;
  const int tx = threadIdx.x, ty = threadIdx.y;
  #pragma unroll
  for(int i=0;i<4;i++) t[ty*4+i][tx] = src[(size_t)(r0+ty*4+i)*C + c0+tx];
  __syncthreads();
  #pragma unroll
  for(int i=0;i<4;i++) dst[(size_t)(c0+ty*4+i)*R + r0+tx] = f2bf(t[tx][ty*4+i]);
}

// ---------- f32 -> bf16 (no transpose), vectorized x4 ----------
__global__ void cvt_kernel(const float* __restrict__ in, u16* __restrict__ out, int n4){
  int i = blockIdx.x*256 + threadIdx.x;
  if(i>=n4) return;
  float4 v = ((const float4*)in)[i];
  ushort4 o; o.x=f2bf(v.x); o.y=f2bf(v.y); o.z=f2bf(v.z); o.w=f2bf(v.w);
  ((ushort4*)out)[i] = o;
}

// ---------- gather + embed + PE + fused LN: emits raw (S,TGT) and LN'd (SY,TGTY) ----------
__global__ __launch_bounds__(256)
void embed_kernel(const float* __restrict__ x_c, const int* __restrict__ idx,
                  const float* __restrict__ Wsrc, const float* __restrict__ Wtgt,
                  u16* __restrict__ S, u16* __restrict__ SY,
                  u16* __restrict__ TGT, u16* __restrict__ TGTY, int g0){
  __shared__ float xs[16][12];
  __shared__ float xt[12];
  __shared__ float sm[16][260];
  __shared__ float mv[16][2];
  __shared__ float wpart[4][2];
  __shared__ float tmv[2];
  const int gl = blockIdx.x, g = gl + g0, b = g>>9, n = g&511, d = threadIdx.x; // 256 thr
  const int w = d>>6, lane = d&63;
  if(d < 192){ int kk=d/12, t=d-kk*12; xs[kk][t] = x_c[(b*12+t)*512 + idx[n*16+kk]]; }
  else if(d < 204){ int t=d-192; xt[t] = x_c[(b*12+t)*512 + n]; }
  __syncthreads();
  float wsr[12], wtg[12];
  #pragma unroll
  for(int t=0;t<12;t++){ wsr[t]=Wsrc[t*256+d]; wtg[t]=Wtgt[t*256+d]; }
  const float freq = expf(-(float)(d & ~1) * (9.210340371976184f/256.0f));
  const bool odd = d & 1;
  float xv[16];
  #pragma unroll
  for(int kk=0;kk<16;kk++){
    float a=0;
    #pragma unroll
    for(int t=0;t<12;t++) a = fmaf(xs[kk][t], wsr[t], a);
    float pe = odd ? cosf(freq*(float)kk) : sinf(freq*(float)kk);
    xv[kk] = a*16.0f + pe;
    S[(size_t)(gl*16+kk)*256 + d] = f2bf(xv[kk]);
    sm[kk][d] = xv[kk];
  }
  float tv;
  {
    float a=0;
    #pragma unroll
    for(int t=0;t<12;t++) a = fmaf(xt[t], wtg[t], a);
    tv = a*16.0f + (odd?1.0f:0.0f);
    TGT[(size_t)gl*256 + d] = f2bf(tv);
  }
  {
    float s2=tv, q2=tv*tv;
    #pragma unroll
    for(int off=32; off>0; off>>=1){ s2+=__shfl_xor(s2,off); q2+=__shfl_xor(q2,off); }
    if(lane==0){ wpart[w][0]=s2; wpart[w][1]=q2; }
  }
  __syncthreads();
  {
    const int kk=d>>4, part=d&15;
    float s=0,q=0;
    #pragma unroll
    for(int t=0;t<16;t++){ float v=sm[kk][part*16+t]; s+=v; q+=v*v; }
    #pragma unroll
    for(int off=1; off<16; off<<=1){ s+=__shfl_xor(s,off); q+=__shfl_xor(q,off); }
    if(part==0){
      float mean=s*(1.0f/256.0f);
      float var=q*(1.0f/256.0f)-mean*mean;
      mv[kk][0]=mean; mv[kk][1]=rsqrtf(var+1e-6f);
    }
    if(d==0){
      float ts=wpart[0][0]+wpart[1][0]+wpart[2][0]+wpart[3][0];
      float tq=wpart[0][1]+wpart[1][1]+wpart[2][1]+wpart[3][1];
      float mean=ts*(1.0f/256.0f);
      float var=tq*(1.0f/256.0f)-mean*mean;
      tmv[0]=mean; tmv[1]=rsqrtf(var+1e-6f);
    }
  }
  __syncthreads();
  #pragma unroll
  for(int kk=0;kk<16;kk++)
    SY[(size_t)(gl*16+kk)*256 + d] = f2bf((xv[kk]-mv[kk][0])*mv[kk][1]);
  TGTY[(size_t)gl*256 + d] = f2bf((tv-tmv[0])*tmv[1]);
}

// ---------- MFMA GEMM: C[M,N] = A[M,K] @ B[K,N], Bt[N][K]. 128x128 tile. ----------
// grid (N/128, M/128): consecutive blocks share the A slab -> A fetched once (L2/L3 hit).
template<int MODE>
__global__ __launch_bounds__(256)
void gemm_mfma(const u16* __restrict__ A, const u16* __restrict__ Bt, u16* __restrict__ C,
               int M, int N, int K)
{
  __shared__ u16 As[128*32];
  __shared__ u16 Bs[128*32];
  const int tid = threadIdx.x;
  const int w = tid>>6, l = tid&63;
  const int quad = l>>4, col16 = l&15;
  const int wr = (w>>1)*64, wc = (w&1)*64;
  const size_t m0 = (size_t)blockIdx.y*128;
  const size_t n0 = (size_t)blockIdx.x*128;

  const int sr = l>>2, sc = (l&3)*8;
  const int ca = w*2, cb = w*2+1;
  const u16* aG0 = A  + (m0 + ca*16 + sr)*K + sc;
  const u16* aG1 = A  + (m0 + cb*16 + sr)*K + sc;
  const u16* bG0 = Bt + (n0 + ca*16 + sr)*K + sc;
  const u16* bG1 = Bt + (n0 + cb*16 + sr)*K + sc;
  u16* aL0 = &As[ca*512];
  u16* aL1 = &As[cb*512];
  u16* bL0 = &Bs[ca*512];
  u16* bL1 = &Bs[cb*512];

  f32x4 acc[4][4];
  #pragma unroll
  for(int i=0;i<4;i++)
    #pragma unroll
    for(int j=0;j<4;j++) acc[i][j] = (f32x4){0.f,0.f,0.f,0.f};

  for(int k0=0;k0<K;k0+=32){
    GLDS(aG0 + k0, aL0);
    GLDS(aG1 + k0, aL1);
    GLDS(bG0 + k0, bL0);
    GLDS(bG1 + k0, bL1);
    __syncthreads();
    short8 af[4], bf[4];
    #pragma unroll
    for(int i=0;i<4;i++) af[i] = *(const short8*)&As[(wr + i*16 + col16)*32 + quad*8];
    #pragma unroll
    for(int j=0;j<4;j++) bf[j] = *(const short8*)&Bs[(wc + j*16 + col16)*32 + quad*8];
    #pragma unroll
    for(int i=0;i<4;i++)
      #pragma unroll
      for(int j=0;j<4;j++)
        acc[i][j] = __builtin_amdgcn_mfma_f32_16x16x32_bf16(af[i], bf[j], acc[i][j], 0,0,0);
    __syncthreads();
  }

  #pragma unroll
  for(int i=0;i<4;i++){
    #pragma unroll
    for(int r=0;r<4;r++){
      const size_t row = m0 + wr + i*16 + quad*4 + r;
      u16* cp = C + row*(size_t)N + n0 + wc + col16;
      #pragma unroll
      for(int j=0;j<4;j++){
        float v = acc[i][j][r];
        if(MODE==2) v += bf2f(cp[j*16]);
        if(MODE==1) v = fmaxf(v, 0.f);
        cp[j*16] = f2bf(v);
      }
    }
  }
}

// ---------- wide MFMA GEMM: 128x256 tile. grid (N/256, M/128): A-slab shared by adjacent blocks.
template<int MODE>
__global__ __launch_bounds__(256,2)
void gemm_wide(const u16* __restrict__ A, const u16* __restrict__ Bt, u16* __restrict__ C,
               int M, int N, int K)
{
  __shared__ u16 As[128*32];
  __shared__ u16 Bs[256*32];
  const int tid = threadIdx.x;
  const int w = tid>>6, l = tid&63;
  const int quad = l>>4, col16 = l&15;
  const int wr = (w>>1)*64, wc = (w&1)*128;
  const size_t m0 = (size_t)blockIdx.y*128;
  const size_t n0 = (size_t)blockIdx.x*256;

  const int sr = l>>2, sc = (l&3)*8;
  const u16* aG0 = A + (m0 + (w*2+0)*16 + sr)*K + sc;
  const u16* aG1 = A + (m0 + (w*2+1)*16 + sr)*K + sc;
  u16* aL0 = &As[(w*2+0)*512];
  u16* aL1 = &As[(w*2+1)*512];
  const u16* bG[4]; u16* bL[4];
  #pragma unroll
  for(int c=0;c<4;c++){
    int ch = w*4+c;
    bG[c] = Bt + (n0 + ch*16 + sr)*K + sc;
    bL[c] = &Bs[ch*512];
  }

  f32x4 acc[4][8];
  #pragma unroll
  for(int i=0;i<4;i++)
    #pragma unroll
    for(int j=0;j<8;j++) acc[i][j] = (f32x4){0.f,0.f,0.f,0.f};

  for(int k0=0;k0<K;k0+=32){
    GLDS(aG0 + k0, aL0);
    GLDS(aG1 + k0, aL1);
    #pragma unroll
    for(int c=0;c<4;c++) GLDS(bG[c] + k0, bL[c]);
    __syncthreads();
    short8 af[4], bf[8];
    #pragma unroll
    for(int i=0;i<4;i++) af[i] = *(const short8*)&As[(wr + i*16 + col16)*32 + quad*8];
    #pragma unroll
    for(int j=0;j<8;j++) bf[j] = *(const short8*)&Bs[(wc + j*16 + col16)*32 + quad*8];
    #pragma unroll
    for(int i=0;i<4;i++)
      #pragma unroll
      for(int j=0;j<8;j++)
        acc[i][j] = __builtin_amdgcn_mfma_f32_16x16x32_bf16(af[i], bf[j], acc[i][j], 0,0,0);
    __syncthreads();
  }

  #pragma unroll
  for(int i=0;i<4;i++){
    #pragma unroll
    for(int r=0;r<4;r++){
      const size_t row = m0 + wr + i*16 + quad*4 + r;
      u16* cp = C + row*(size_t)N + n0 + wc + col16;
      #pragma unroll
      for(int j=0;j<8;j++){
        float v = acc[i][j][r];
        if(MODE==1) v = fmaxf(v, 0.f);
        cp[j*16] = f2bf(v);
      }
    }
  }
}

// ---------- fused GEMM + residual-add + LayerNorm.  N fixed = 256. ----------
__global__ __launch_bounds__(256,2)
void gemm_addln(const u16* __restrict__ A, const u16* __restrict__ Bt,
                u16* __restrict__ C, u16* __restrict__ Y, int M, int K)
{
  __shared__ u16 As[128*32];
  __shared__ u16 Bs[256*32];
  __shared__ float ssum[128][2];
  __shared__ float ssq[128][2];
  const int tid = threadIdx.x;
  const int w = tid>>6, l = tid&63;
  const int quad = l>>4, col16 = l&15;
  const int wr = (w>>1)*64, wc = (w&1)*128;
  const int wh = w&1;
  const size_t m0 = (size_t)blockIdx.x*128;

  const int sr = l>>2, sc = (l&3)*8;
  const u16* aG0 = A + (m0 + (w*2+0)*16 + sr)*K + sc;
  const u16* aG1 = A + (m0 + (w*2+1)*16 + sr)*K + sc;
  u16* aL0 = &As[(w*2+0)*512];
  u16* aL1 = &As[(w*2+1)*512];
  const u16* bG[4]; u16* bL[4];
  #pragma unroll
  for(int c=0;c<4;c++){
    int ch = w*4+c;
    bG[c] = Bt + (size_t)(ch*16 + sr)*K + sc;
    bL[c] = &Bs[ch*512];
  }

  f32x4 acc[4][8];
  #pragma unroll
  for(int i=0;i<4;i++)
    #pragma unroll
    for(int j=0;j<8;j++) acc[i][j] = (f32x4){0.f,0.f,0.f,0.f};

  for(int k0=0;k0<K;k0+=32){
    GLDS(aG0 + k0, aL0);
    GLDS(aG1 + k0, aL1);
    #pragma unroll
    for(int c=0;c<4;c++) GLDS(bG[c] + k0, bL[c]);
    __syncthreads();
    short8 af[4], bf[8];
    #pragma unroll
    for(int i=0;i<4;i++) af[i] = *(const short8*)&As[(wr + i*16 + col16)*32 + quad*8];
    #pragma unroll
    for(int j=0;j<8;j++) bf[j] = *(const short8*)&Bs[(wc + j*16 + col16)*32 + quad*8];
    #pragma unroll
    for(int i=0;i<4;i++)
      #pragma unroll
      for(int j=0;j<8;j++)
        acc[i][j] = __builtin_amdgcn_mfma_f32_16x16x32_bf16(af[i], bf[j], acc[i][j], 0,0,0);
    __syncthreads();
  }

  #pragma unroll
  for(int i=0;i<4;i++){
    #pragma unroll
    for(int r=0;r<4;r++){
      const int lr = wr + i*16 + quad*4 + r;
      const u16* cp = C + (m0 + lr)*(size_t)256 + wc + col16;
      float s=0.f, q=0.f;
      #pragma unroll
      for(int j=0;j<8;j++){
        float v = acc[i][j][r] + bf2f(cp[j*16]);
        acc[i][j][r] = v;
        s += v; q += v*v;
      }
      #pragma unroll
      for(int off=1; off<16; off<<=1){ s+=__shfl_xor(s,off); q+=__shfl_xor(q,off); }
      if(col16==0){ ssum[lr][wh]=s; ssq[lr][wh]=q; }
    }
  }
  __syncthreads();
  #pragma unroll
  for(int i=0;i<4;i++){
    #pragma unroll
    for(int r=0;r<4;r++){
      const int lr = wr + i*16 + quad*4 + r;
      const float mean = (ssum[lr][0]+ssum[lr][1])*(1.0f/256.0f);
      const float var  = (ssq[lr][0]+ssq[lr][1])*(1.0f/256.0f) - mean*mean;
      const float rs   = rsqrtf(var + 1e-6f);
      u16* cp = C + (m0 + lr)*(size_t)256 + wc + col16;
      u16* yp = Y + (m0 + lr)*(size_t)256 + wc + col16;
      #pragma unroll
      for(int j=0;j<8;j++){
        float v = acc[i][j][r];
        cp[j*16] = f2bf(v);
        yp[j*16] = f2bf((v-mean)*rs);
      }
    }
  }
}

// ---------- encoder self-attention: QKV packed [M][768]; 1 group per 256-thr block ----------
__global__ __launch_bounds__(256)
void attn_enc_kernel(const u16* __restrict__ QKV, u16* __restrict__ O){
  __shared__ u16 sb[12672];
  const int tid = threadIdx.x;
  const size_t g = blockIdx.x;
  const size_t grow = g*16;
  #pragma unroll
  for(int it=0; it<6; it++){
    int e = (tid + 256*it)*8;
    int r = e/768, c = e - r*768;
    int t = c>>8, cc = c&255;
    *(uint4*)&sb[t*4224 + r*264 + cc] = *(const uint4*)&QKV[(grow+r)*768 + c];
  }
  __syncthreads();
  const int h = tid>>5, q = (tid>>1)&15, eh = tid&1;
  const int eo = h*32 + eh*16;
  float qv[16];
  #pragma unroll
  for(int e2=0;e2<8;e2++){
    u32 x = *(const u32*)&sb[q*264 + eo + e2*2];
    qv[2*e2]=bfLO(x); qv[2*e2+1]=bfHI(x);
  }
  float sc[16];
  #pragma unroll
  for(int kk=0;kk<16;kk++){
    const u16* kr = &sb[4224 + kk*264 + eo];
    float s=0;
    #pragma unroll
    for(int e2=0;e2<8;e2++){
      u32 x = *(const u32*)&kr[e2*2];
      s = fmaf(qv[2*e2], bfLO(x), s);
      s = fmaf(qv[2*e2+1], bfHI(x), s);
    }
    s += __shfl_xor(s, 1);
    sc[kk] = s*0.17677669529663687f;
  }
  float m=sc[0];
  #pragma unroll
  for(int kk=1;kk<16;kk++) m=fmaxf(m,sc[kk]);
  float sum=0;
  #pragma unroll
  for(int kk=0;kk<16;kk++){ sc[kk]=expf(sc[kk]-m); sum+=sc[kk]; }
  float inv=1.0f/sum;
  float ov[16];
  #pragma unroll
  for(int e=0;e<16;e++) ov[e]=0.f;
  #pragma unroll
  for(int kk=0;kk<16;kk++){
    float p = sc[kk]*inv;
    const u16* vr = &sb[8448 + kk*264 + eo];
    #pragma unroll
    for(int e2=0;e2<8;e2++){
      u32 x = *(const u32*)&vr[e2*2];
      ov[2*e2]   = fmaf(p, bfLO(x), ov[2*e2]);
      ov[2*e2+1] = fmaf(p, bfHI(x), ov[2*e2+1]);
    }
  }
  u16* op = O + (grow+q)*256 + eo;
  #pragma unroll
  for(int b=0;b<4;b++){
    ushort4 t4; t4.x=f2bf(ov[4*b]); t4.y=f2bf(ov[4*b+1]); t4.z=f2bf(ov[4*b+2]); t4.w=f2bf(ov[4*b+3]);
    *(ushort4*)&op[b*4] = t4;
  }
}

// ---------- decoder cross-attention: bf16 LDS staging ----------
__global__ __launch_bounds__(256)
void attn_cross_kernel(const u16* __restrict__ Qc, const u16* __restrict__ KV,
                       u16* __restrict__ Oc, int loff){
  __shared__ float qs[256];
  __shared__ u16 kv[2][16*264];
  __shared__ float aw[128];
  const int t = threadIdx.x;
  const size_t g = blockIdx.x;
  qs[t] = bf2f(Qc[g*256+t]);
  #pragma unroll
  for(int it=0; it<4; it++){
    int e = (t + 256*it)*4;
    int r = e>>8, c = e&255;
    const u16* p = KV + (g*16+r)*1024 + loff + c;
    *(ushort4*)&kv[0][r*264 + c] = *(const ushort4*)p;        // K
    *(ushort4*)&kv[1][r*264 + c] = *(const ushort4*)(p+256);  // V
  }
  __syncthreads();
  if(t<128){
    int h=t>>4, j=t&15;
    const u16* kr = &kv[0][j*264 + h*32];
    const float* qq = &qs[h*32];
    float s=0;
    #pragma unroll
    for(int e2=0;e2<16;e2++){
      u32 x = *(const u32*)&kr[e2*2];
      s = fmaf(qq[2*e2],   bfLO(x), s);
      s = fmaf(qq[2*e2+1], bfHI(x), s);
    }
    aw[h*16+j] = s*0.17677669529663687f;
  }
  __syncthreads();
  if(t<8){
    float m=-1e30f;
    for(int j=0;j<16;j++) m=fmaxf(m, aw[t*16+j]);
    float sum=0;
    for(int j=0;j<16;j++){ float e=expf(aw[t*16+j]-m); aw[t*16+j]=e; sum+=e; }
    float inv=1.0f/sum;
    for(int j=0;j<16;j++) aw[t*16+j]*=inv;
  }
  __syncthreads();
  {
    int h=t>>5, e=t&31;
    float o=0;
    #pragma unroll
    for(int j=0;j<16;j++) o = fmaf(aw[h*16+j], bf2f(kv[1][j*264 + h*32 + e]), o);
    Oc[g*256+t] = f2bf(o);
  }
}

// ---------- final: out[g0+gl, :12] = tY[gl] @ W_gen (fp32 out) ----------
__global__ __launch_bounds__(64)
void final_kernel(const u16* __restrict__ TY, const float* __restrict__ Wg, float* __restrict__ out, int g0){
  __shared__ float y[256];
  const int lane = threadIdx.x;
  const size_t gl = blockIdx.x;
  ushort4 u = *(const ushort4*)(TY + gl*256 + (size_t)lane*4);
  y[lane*4+0]=bf2f(u.x); y[lane*4+1]=bf2f(u.y); y[lane*4+2]=bf2f(u.z); y[lane*4+3]=bf2f(u.w);
  __syncthreads();
  if(lane<12){
    float s=0;
    for(int d=0;d<256;d++) s = fmaf(y[d], Wg[d*12+lane], s);
    out[(g0+gl)*12+lane]=s;
  }
}

extern "C" void kernel_launch(void* const* d_in, const int* in_sizes, int n_in,
                              void* d_out, int out_size, void* d_ws, size_t ws_size,
                              hipStream_t stream)
{
  (void)in_sizes; (void)n_in; (void)out_size;
  const float* x_c  = (const float*)d_in[0];
  const float* A    = (const float*)d_in[1];
  const float* Wsrc = (const float*)d_in[2];
  const float* Wtgt = (const float*)d_in[3];
  const float* wsrc_f[7] = {(const float*)d_in[4],(const float*)d_in[5],(const float*)d_in[6],
                            (const float*)d_in[7],(const float*)d_in[8],(const float*)d_in[9],
                            (const float*)d_in[10]};
  const float* W_gen = (const float*)d_in[11];
  float* out = (float*)d_out;

  // ---- choose chunk size GC (groups per chunk) to fit ws_size ----
  auto align256 = [](size_t b)->size_t{ return (b + 255) & ~(size_t)255; };
  auto need_bytes = [&](int GC)->size_t{
    size_t b = 0;
    b += align256(512*16*4);
    for(int i=0;i<7;i++) b += align256((size_t)524288*2);
    b += align256((size_t)4*65536*2);        // wKV pack
    b += align256((size_t)2*65536*2)*2;      // wv_plain, wVO
    b += align256((size_t)GC*16*256*2)*2;    // cS, cY
    b += align256((size_t)GC*16*1024*2);     // big (QKV 768 / Tc 1024 / KVc 1024)
    b += align256((size_t)GC*256*2)*4;       // tgt, tY, tA, tO
    b += align256((size_t)GC*1024*2);        // tT
    return b;
  };
  int GC = 8192;
  while(GC > 128 && need_bytes(GC) > ws_size) GC >>= 1;

  // ---- workspace carve ----
  char* ws = (char*)d_ws;
  size_t off = 0;
  auto alloc = [&](size_t bytes)->char*{
    char* p = ws + off;
    off += (bytes + 255) & ~(size_t)255;
    return p;
  };
  int* idx = (int*)alloc(512*16*4);
  u16* wt[7];
  for(int i=0;i<7;i++) wt[i] = (u16*)alloc((size_t)524288*2);   // transposed bf16 weights
  u16* wKV      = (u16*)alloc((size_t)4*65536*2);  // [Wk0T|Wv0T|Wk1T|Wv1T] rows
  u16* wv_plain = (u16*)alloc((size_t)2*65536*2);  // dec_self Wv, plain bf16
  u16* wVO      = (u16*)alloc((size_t)2*65536*2);  // (Wv@Wo)^T per layer
  u16* cS  = (u16*)alloc((size_t)GC*16*256*2);
  u16* cY  = (u16*)alloc((size_t)GC*16*256*2);
  u16* big = (u16*)alloc((size_t)GC*16*1024*2);
  u16* tgt = (u16*)alloc((size_t)GC*256*2);
  u16* tY  = (u16*)alloc((size_t)GC*256*2);
  u16* tA  = (u16*)alloc((size_t)GC*256*2);
  u16* tO  = (u16*)alloc((size_t)GC*256*2);
  u16* tT  = (u16*)alloc((size_t)GC*1024*2);

  u16* wQKV = big;   // [Mr][768]  encoder attn phase
  u16* Tc   = big;   // [Mr][1024] encoder FFN phase
  u16* KVc  = big;   // [Mr][1024] decoder cross phase (both layers)

  // weights -> transposed bf16 (Bt[N][K]); all 7 tensors are 524288 elems
  {
    dim3 blk(32,8);
    tcvt_kernel<<<dim3( 256/32, 256/32, 8), blk, 0, stream>>>(wsrc_f[0], wt[0], 256, 256);
    tcvt_kernel<<<dim3(1024/32, 256/32, 2), blk, 0, stream>>>(wsrc_f[1], wt[1], 256,1024);
    tcvt_kernel<<<dim3( 256/32,1024/32, 2), blk, 0, stream>>>(wsrc_f[2], wt[2],1024, 256);
    tcvt_kernel<<<dim3( 256/32, 256/32, 8), blk, 0, stream>>>(wsrc_f[3], wt[3], 256, 256);
    tcvt_kernel<<<dim3( 256/32, 256/32, 8), blk, 0, stream>>>(wsrc_f[4], wt[4], 256, 256);
    tcvt_kernel<<<dim3(1024/32, 256/32, 2), blk, 0, stream>>>(wsrc_f[5], wt[5], 256,1024);
    tcvt_kernel<<<dim3( 256/32,1024/32, 2), blk, 0, stream>>>(wsrc_f[6], wt[6],1024, 256);
  }
  topk_kernel<<<512,64,0,stream>>>(A, idx);

  // pack cross-attn KV weights: rows [Wk0T | Wv0T | Wk1T | Wv1T]  (each slice 65536 u16)
  hipMemcpyAsync(wKV+0*65536, wt[4]+1*65536, 65536*2, hipMemcpyDeviceToDevice, stream);
  hipMemcpyAsync(wKV+1*65536, wt[4]+2*65536, 65536*2, hipMemcpyDeviceToDevice, stream);
  hipMemcpyAsync(wKV+2*65536, wt[4]+5*65536, 65536*2, hipMemcpyDeviceToDevice, stream);
  hipMemcpyAsync(wKV+3*65536, wt[4]+6*65536, 65536*2, hipMemcpyDeviceToDevice, stream);

  // precompute Wvo_t[l] = (Wv@Wo)^T for decoder self-attn (softmax over 1 key == identity)
  for(int l=0;l<2;l++){
    cvt_kernel<<<64,256,0,stream>>>(wsrc_f[3]+(size_t)(l*4+2)*65536, wv_plain+(size_t)l*65536, 16384);
    gemm_mfma<0><<<dim3(2,2),256,0,stream>>>(wt[3]+(size_t)(l*4+3)*65536, wv_plain+(size_t)l*65536,
                                             wVO+(size_t)l*65536, 256,256,256);
  }

  auto gemm = [&](const u16* Am, const u16* Bm, u16* Cm, int M_, int N_, int K_, int mode){
    dim3 grid(N_/128, M_/128);
    if(mode==1)      gemm_mfma<1><<<grid,256,0,stream>>>(Am,Bm,Cm,M_,N_,K_);
    else if(mode==2) gemm_mfma<2><<<grid,256,0,stream>>>(Am,Bm,Cm,M_,N_,K_);
    else             gemm_mfma<0><<<grid,256,0,stream>>>(Am,Bm,Cm,M_,N_,K_);
  };
  auto gemmw = [&](const u16* Am, const u16* Bm, u16* Cm, int M_, int N_, int K_, int mode){
    dim3 grid(N_/256, M_/128);
    if(mode==1) gemm_wide<1><<<grid,256,0,stream>>>(Am,Bm,Cm,M_,N_,K_);
    else        gemm_wide<0><<<grid,256,0,stream>>>(Am,Bm,Cm,M_,N_,K_);
  };
  auto gemm_ln = [&](const u16* Am, const u16* Bm, u16* Cm, u16* Ym, int M_, int K_){
    gemm_addln<<<dim3(M_/128),256,0,stream>>>(Am,Bm,Cm,Ym,M_,K_);
  };

  const int Mr = GC*16;   // encoder rows per chunk
  const int Md = GC;      // decoder rows per chunk

  for(int g0=0; g0<8192; g0+=GC){
    embed_kernel<<<GC,256,0,stream>>>(x_c, idx, Wsrc, Wtgt, cS, cY, tgt, tY, g0);

    // ---- encoder (L=2) ----
    for(int l=0;l<2;l++){
      const u16* Wat = wt[0] + (size_t)l*4*65536;
      gemmw(cY, Wat, wQKV, Mr, 768, 256, 0);           // Q|K|V packed (A = LN'd stream)
      attn_enc_kernel<<<GC,256,0,stream>>>(wQKV, cY);
      gemm_ln(cY, Wat+3*65536, cS, cY, Mr, 256);       // src += O@Wo ; cY = LN(src)
      gemmw(cY, wt[1]+(size_t)l*262144, Tc, Mr,1024, 256, 1);  // relu(y@F1)
      gemm_ln(Tc, wt[2]+(size_t)l*262144, cS, cY, Mr, 1024);   // src += t@F2 ; cY = LN(src)
    }
    // after layer 1, cY == LN(src) == memory
    gemmw(cY, wKV, KVc, Mr, 1024, 256, 0);             // K,V for BOTH decoder layers

    // ---- decoder (L=2) ----
    for(int l=0;l<2;l++){
      const u16* Wdc = wt[4] + (size_t)l*4*65536;
      // self-attn on 1 token: tgt += LN(tgt) @ (Wv@Wo) ; tY refreshed
      gemm_ln(tY, wVO+(size_t)l*65536, tgt, tY, Md, 256);
      // cross-attn
      gemm(tY, Wdc, tA, Md, 256, 256, 0);              // Qc
      attn_cross_kernel<<<GC,256,0,stream>>>(tA, KVc, tO, l*512);
      gemm_ln(tO, Wdc+3*65536, tgt, tY, Md, 256);      // tgt += attn@Wo ; tY = LN(tgt)
      // FFN
      gemmw(tY, wt[5]+(size_t)l*262144, tT, Md,1024, 256, 1);
      gemm_ln(tT, wt[6]+(size_t)l*262144, tgt, tY, Md, 1024);  // tgt += ; tY = LN(tgt)
    }

    final_kernel<<<GC,64,0,stream>>>(tY, W_gen, out, g0);
  }
}

// Round 14
// 1707.555 us; speedup vs baseline: 1.0643x; 1.0643x over previous
//
#include <hip/hip_runtime.h>

typedef unsigned short u16;
typedef unsigned int u32;
typedef __attribute__((ext_vector_type(8))) short short8;   // 8 bf16 (4 VGPRs)
typedef __attribute__((ext_vector_type(4))) float f32x4;    // MFMA acc

// ---------- bf16 helpers ----------
__device__ __forceinline__ float bf2f(unsigned v){ union{unsigned u; float f;} c; c.u = v<<16; return c.f; }
__device__ __forceinline__ u16 f2bf(float f){
  union{float f; unsigned u;} c; c.f=f;
  unsigned u = c.u;
  u += 0x7fffu + ((u>>16)&1u);
  return (u16)(u>>16);
}
__device__ __forceinline__ float bfLO(u32 x){ union{u32 u; float f;} c; c.u = x<<16;        return c.f; }
__device__ __forceinline__ float bfHI(u32 x){ union{u32 u; float f;} c; c.u = x&0xffff0000u; return c.f; }

#define GLDS(g, l) __builtin_amdgcn_global_load_lds( \
    (const __attribute__((address_space(1))) void*)(g), \
    (__attribute__((address_space(3))) void*)(l), 16, 0, 0)

// ---------- top-K=16 of each row of A (512x512), descending, stable ----------
__global__ void topk_kernel(const float* __restrict__ A, int* __restrict__ idx){
  __shared__ float vals[512];
  const int n = blockIdx.x, t = threadIdx.x; // 64 threads = 1 wave
  for(int i=t;i<512;i+=64) vals[i] = A[n*512+i];
  __syncthreads();
  for(int kk=0;kk<16;kk++){
    float bv = -1e30f; int bi = 1<<30;
    for(int i=t;i<512;i+=64){
      float v = vals[i];
      if(v > bv){ bv=v; bi=i; }
    }
    #pragma unroll
    for(int off=32; off>0; off>>=1){
      float ov = __shfl_down(bv, off);
      int   oi = __shfl_down(bi, off);
      if(ov > bv || (ov==bv && oi<bi)){ bv=ov; bi=oi; }
    }
    bi = __shfl(bi, 0);
    if(t==0){ idx[n*16+kk] = bi; vals[bi] = -1e30f; }
    __syncthreads();
  }
}

// ---------- transpose + f32->bf16: [R][C] -> [C][R] bf16, batched over z ----------
__global__ __launch_bounds__(256)
void tcvt_kernel(const float* __restrict__ src, u16* __restrict__ dst, int R, int C){
  __shared__ float t[32][33];
  const int m = blockIdx.z;
  src += (size_t)m*R*C; dst += (size_t)m*R*C;
  const int c0 = blockIdx.x*32, r0 = blockIdx.y*32;
  const int tx = threadIdx.x, ty = threadIdx.y;
  #pragma unroll
  for(int i=0;i<4;i++) t[ty*4+i][tx] = src[(size_t)(r0+ty*4+i)*C + c0+tx];
  __syncthreads();
  #pragma unroll
  for(int i=0;i<4;i++) dst[(size_t)(c0+ty*4+i)*R + r0+tx] = f2bf(t[tx][ty*4+i]);
}

// ---------- f32 -> bf16 (no transpose), vectorized x4 ----------
__global__ void cvt_kernel(const float* __restrict__ in, u16* __restrict__ out, int n4){
  int i = blockIdx.x*256 + threadIdx.x;
  if(i>=n4) return;
  float4 v = ((const float4*)in)[i];
  ushort4 o; o.x=f2bf(v.x); o.y=f2bf(v.y); o.z=f2bf(v.z); o.w=f2bf(v.w);
  ((ushort4*)out)[i] = o;
}

// ---------- gather + embed + PE + fused LN: emits raw (S,TGT) and LN'd (SY,TGTY) ----------
__global__ __launch_bounds__(256)
void embed_kernel(const float* __restrict__ x_c, const int* __restrict__ idx,
                  const float* __restrict__ Wsrc, const float* __restrict__ Wtgt,
                  u16* __restrict__ S, u16* __restrict__ SY,
                  u16* __restrict__ TGT, u16* __restrict__ TGTY, int g0){
  __shared__ float xs[16][12];
  __shared__ float xt[12];
  __shared__ float sm[16][260];
  __shared__ float mv[16][2];
  __shared__ float wpart[4][2];
  __shared__ float tmv[2];
  const int gl = blockIdx.x, g = gl + g0, b = g>>9, n = g&511, d = threadIdx.x; // 256 thr
  const int w = d>>6, lane = d&63;
  if(d < 192){ int kk=d/12, t=d-kk*12; xs[kk][t] = x_c[(b*12+t)*512 + idx[n*16+kk]]; }
  else if(d < 204){ int t=d-192; xt[t] = x_c[(b*12+t)*512 + n]; }
  __syncthreads();
  float wsr[12], wtg[12];
  #pragma unroll
  for(int t=0;t<12;t++){ wsr[t]=Wsrc[t*256+d]; wtg[t]=Wtgt[t*256+d]; }
  const float freq = expf(-(float)(d & ~1) * (9.210340371976184f/256.0f));
  const bool odd = d & 1;
  float xv[16];
  #pragma unroll
  for(int kk=0;kk<16;kk++){
    float a=0;
    #pragma unroll
    for(int t=0;t<12;t++) a = fmaf(xs[kk][t], wsr[t], a);
    float pe = odd ? cosf(freq*(float)kk) : sinf(freq*(float)kk);
    xv[kk] = a*16.0f + pe;
    S[(size_t)(gl*16+kk)*256 + d] = f2bf(xv[kk]);
    sm[kk][d] = xv[kk];
  }
  float tv;
  {
    float a=0;
    #pragma unroll
    for(int t=0;t<12;t++) a = fmaf(xt[t], wtg[t], a);
    tv = a*16.0f + (odd?1.0f:0.0f);
    TGT[(size_t)gl*256 + d] = f2bf(tv);
  }
  {
    float s2=tv, q2=tv*tv;
    #pragma unroll
    for(int off=32; off>0; off>>=1){ s2+=__shfl_xor(s2,off); q2+=__shfl_xor(q2,off); }
    if(lane==0){ wpart[w][0]=s2; wpart[w][1]=q2; }
  }
  __syncthreads();
  {
    const int kk=d>>4, part=d&15;
    float s=0,q=0;
    #pragma unroll
    for(int t=0;t<16;t++){ float v=sm[kk][part*16+t]; s+=v; q+=v*v; }
    #pragma unroll
    for(int off=1; off<16; off<<=1){ s+=__shfl_xor(s,off); q+=__shfl_xor(q,off); }
    if(part==0){
      float mean=s*(1.0f/256.0f);
      float var=q*(1.0f/256.0f)-mean*mean;
      mv[kk][0]=mean; mv[kk][1]=rsqrtf(var+1e-6f);
    }
    if(d==0){
      float ts=wpart[0][0]+wpart[1][0]+wpart[2][0]+wpart[3][0];
      float tq=wpart[0][1]+wpart[1][1]+wpart[2][1]+wpart[3][1];
      float mean=ts*(1.0f/256.0f);
      float var=tq*(1.0f/256.0f)-mean*mean;
      tmv[0]=mean; tmv[1]=rsqrtf(var+1e-6f);
    }
  }
  __syncthreads();
  #pragma unroll
  for(int kk=0;kk<16;kk++)
    SY[(size_t)(gl*16+kk)*256 + d] = f2bf((xv[kk]-mv[kk][0])*mv[kk][1]);
  TGTY[(size_t)gl*256 + d] = f2bf((tv-tmv[0])*tmv[1]);
}

// ---------- MFMA GEMM: C[M,N] = A[M,K] @ B[K,N], Bt[N][K]. 128x128 tile. ----------
// MODE: 0 none, 1 relu, 2 add-residual.
template<int MODE>
__global__ __launch_bounds__(256)
void gemm_mfma(const u16* __restrict__ A, const u16* __restrict__ Bt, u16* __restrict__ C,
               int M, int N, int K)
{
  __shared__ u16 As[128*32];
  __shared__ u16 Bs[128*32];
  const int tid = threadIdx.x;
  const int w = tid>>6, l = tid&63;
  const int quad = l>>4, col16 = l&15;
  const int wr = (w>>1)*64, wc = (w&1)*64;
  const size_t m0 = (size_t)blockIdx.x*128;
  const size_t n0 = (size_t)blockIdx.y*128;

  const int sr = l>>2, sc = (l&3)*8;
  const int ca = w*2, cb = w*2+1;
  const u16* aG0 = A  + (m0 + ca*16 + sr)*K + sc;
  const u16* aG1 = A  + (m0 + cb*16 + sr)*K + sc;
  const u16* bG0 = Bt + (n0 + ca*16 + sr)*K + sc;
  const u16* bG1 = Bt + (n0 + cb*16 + sr)*K + sc;
  u16* aL0 = &As[ca*512];
  u16* aL1 = &As[cb*512];
  u16* bL0 = &Bs[ca*512];
  u16* bL1 = &Bs[cb*512];

  f32x4 acc[4][4];
  #pragma unroll
  for(int i=0;i<4;i++)
    #pragma unroll
    for(int j=0;j<4;j++) acc[i][j] = (f32x4){0.f,0.f,0.f,0.f};

  for(int k0=0;k0<K;k0+=32){
    GLDS(aG0 + k0, aL0);
    GLDS(aG1 + k0, aL1);
    GLDS(bG0 + k0, bL0);
    GLDS(bG1 + k0, bL1);
    __syncthreads();
    short8 af[4], bf[4];
    #pragma unroll
    for(int i=0;i<4;i++) af[i] = *(const short8*)&As[(wr + i*16 + col16)*32 + quad*8];
    #pragma unroll
    for(int j=0;j<4;j++) bf[j] = *(const short8*)&Bs[(wc + j*16 + col16)*32 + quad*8];
    #pragma unroll
    for(int i=0;i<4;i++)
      #pragma unroll
      for(int j=0;j<4;j++)
        acc[i][j] = __builtin_amdgcn_mfma_f32_16x16x32_bf16(af[i], bf[j], acc[i][j], 0,0,0);
    __syncthreads();
  }

  #pragma unroll
  for(int i=0;i<4;i++){
    #pragma unroll
    for(int r=0;r<4;r++){
      const size_t row = m0 + wr + i*16 + quad*4 + r;
      u16* cp = C + row*(size_t)N + n0 + wc + col16;
      #pragma unroll
      for(int j=0;j<4;j++){
        float v = acc[i][j][r];
        if(MODE==2) v += bf2f(cp[j*16]);
        if(MODE==1) v = fmaxf(v, 0.f);
        cp[j*16] = f2bf(v);
      }
    }
  }
}

// ---------- wide MFMA GEMM: 128x256 tile. grid (M/128, N/256). ----------
template<int MODE>
__global__ __launch_bounds__(256,2)
void gemm_wide(const u16* __restrict__ A, const u16* __restrict__ Bt, u16* __restrict__ C,
               int M, int N, int K)
{
  __shared__ u16 As[128*32];
  __shared__ u16 Bs[256*32];
  const int tid = threadIdx.x;
  const int w = tid>>6, l = tid&63;
  const int quad = l>>4, col16 = l&15;
  const int wr = (w>>1)*64, wc = (w&1)*128;
  const size_t m0 = (size_t)blockIdx.x*128;
  const size_t n0 = (size_t)blockIdx.y*256;

  const int sr = l>>2, sc = (l&3)*8;
  const u16* aG0 = A + (m0 + (w*2+0)*16 + sr)*K + sc;
  const u16* aG1 = A + (m0 + (w*2+1)*16 + sr)*K + sc;
  u16* aL0 = &As[(w*2+0)*512];
  u16* aL1 = &As[(w*2+1)*512];
  const u16* bG[4]; u16* bL[4];
  #pragma unroll
  for(int c=0;c<4;c++){
    int ch = w*4+c;
    bG[c] = Bt + (n0 + ch*16 + sr)*K + sc;
    bL[c] = &Bs[ch*512];
  }

  f32x4 acc[4][8];
  #pragma unroll
  for(int i=0;i<4;i++)
    #pragma unroll
    for(int j=0;j<8;j++) acc[i][j] = (f32x4){0.f,0.f,0.f,0.f};

  for(int k0=0;k0<K;k0+=32){
    GLDS(aG0 + k0, aL0);
    GLDS(aG1 + k0, aL1);
    #pragma unroll
    for(int c=0;c<4;c++) GLDS(bG[c] + k0, bL[c]);
    __syncthreads();
    short8 af[4], bf[8];
    #pragma unroll
    for(int i=0;i<4;i++) af[i] = *(const short8*)&As[(wr + i*16 + col16)*32 + quad*8];
    #pragma unroll
    for(int j=0;j<8;j++) bf[j] = *(const short8*)&Bs[(wc + j*16 + col16)*32 + quad*8];
    #pragma unroll
    for(int i=0;i<4;i++)
      #pragma unroll
      for(int j=0;j<8;j++)
        acc[i][j] = __builtin_amdgcn_mfma_f32_16x16x32_bf16(af[i], bf[j], acc[i][j], 0,0,0);
    __syncthreads();
  }

  #pragma unroll
  for(int i=0;i<4;i++){
    #pragma unroll
    for(int r=0;r<4;r++){
      const size_t row = m0 + wr + i*16 + quad*4 + r;
      u16* cp = C + row*(size_t)N + n0 + wc + col16;
      #pragma unroll
      for(int j=0;j<8;j++){
        float v = acc[i][j][r];
        if(MODE==1) v = fmaxf(v, 0.f);
        cp[j*16] = f2bf(v);
      }
    }
  }
}

// ---------- fused GEMM + residual-add + LayerNorm.  N fixed = 256. ----------
__global__ __launch_bounds__(256,2)
void gemm_addln(const u16* __restrict__ A, const u16* __restrict__ Bt,
                u16* __restrict__ C, u16* __restrict__ Y, int M, int K)
{
  __shared__ u16 As[128*32];
  __shared__ u16 Bs[256*32];
  __shared__ float ssum[128][2];
  __shared__ float ssq[128][2];
  const int tid = threadIdx.x;
  const int w = tid>>6, l = tid&63;
  const int quad = l>>4, col16 = l&15;
  const int wr = (w>>1)*64, wc = (w&1)*128;
  const int wh = w&1;
  const size_t m0 = (size_t)blockIdx.x*128;

  const int sr = l>>2, sc = (l&3)*8;
  const u16* aG0 = A + (m0 + (w*2+0)*16 + sr)*K + sc;
  const u16* aG1 = A + (m0 + (w*2+1)*16 + sr)*K + sc;
  u16* aL0 = &As[(w*2+0)*512];
  u16* aL1 = &As[(w*2+1)*512];
  const u16* bG[4]; u16* bL[4];
  #pragma unroll
  for(int c=0;c<4;c++){
    int ch = w*4+c;
    bG[c] = Bt + (size_t)(ch*16 + sr)*K + sc;
    bL[c] = &Bs[ch*512];
  }

  f32x4 acc[4][8];
  #pragma unroll
  for(int i=0;i<4;i++)
    #pragma unroll
    for(int j=0;j<8;j++) acc[i][j] = (f32x4){0.f,0.f,0.f,0.f};

  for(int k0=0;k0<K;k0+=32){
    GLDS(aG0 + k0, aL0);
    GLDS(aG1 + k0, aL1);
    #pragma unroll
    for(int c=0;c<4;c++) GLDS(bG[c] + k0, bL[c]);
    __syncthreads();
    short8 af[4], bf[8];
    #pragma unroll
    for(int i=0;i<4;i++) af[i] = *(const short8*)&As[(wr + i*16 + col16)*32 + quad*8];
    #pragma unroll
    for(int j=0;j<8;j++) bf[j] = *(const short8*)&Bs[(wc + j*16 + col16)*32 + quad*8];
    #pragma unroll
    for(int i=0;i<4;i++)
      #pragma unroll
      for(int j=0;j<8;j++)
        acc[i][j] = __builtin_amdgcn_mfma_f32_16x16x32_bf16(af[i], bf[j], acc[i][j], 0,0,0);
    __syncthreads();
  }

  #pragma unroll
  for(int i=0;i<4;i++){
    #pragma unroll
    for(int r=0;r<4;r++){
      const int lr = wr + i*16 + quad*4 + r;
      const u16* cp = C + (m0 + lr)*(size_t)256 + wc + col16;
      float s=0.f, q=0.f;
      #pragma unroll
      for(int j=0;j<8;j++){
        float v = acc[i][j][r] + bf2f(cp[j*16]);
        acc[i][j][r] = v;
        s += v; q += v*v;
      }
      #pragma unroll
      for(int off=1; off<16; off<<=1){ s+=__shfl_xor(s,off); q+=__shfl_xor(q,off); }
      if(col16==0){ ssum[lr][wh]=s; ssq[lr][wh]=q; }
    }
  }
  __syncthreads();
  #pragma unroll
  for(int i=0;i<4;i++){
    #pragma unroll
    for(int r=0;r<4;r++){
      const int lr = wr + i*16 + quad*4 + r;
      const float mean = (ssum[lr][0]+ssum[lr][1])*(1.0f/256.0f);
      const float var  = (ssq[lr][0]+ssq[lr][1])*(1.0f/256.0f) - mean*mean;
      const float rs   = rsqrtf(var + 1e-6f);
      u16* cp = C + (m0 + lr)*(size_t)256 + wc + col16;
      u16* yp = Y + (m0 + lr)*(size_t)256 + wc + col16;
      #pragma unroll
      for(int j=0;j<8;j++){
        float v = acc[i][j][r];
        cp[j*16] = f2bf(v);
        yp[j*16] = f2bf((v-mean)*rs);
      }
    }
  }
}

// ---------- encoder self-attention: QKV packed [M][768]; 1 group per 256-thr block ----------
__global__ __launch_bounds__(256)
void attn_enc_kernel(const u16* __restrict__ QKV, u16* __restrict__ O){
  __shared__ u16 sb[12672];
  const int tid = threadIdx.x;
  const size_t g = blockIdx.x;
  const size_t grow = g*16;
  #pragma unroll
  for(int it=0; it<6; it++){
    int e = (tid + 256*it)*8;
    int r = e/768, c = e - r*768;
    int t = c>>8, cc = c&255;
    *(uint4*)&sb[t*4224 + r*264 + cc] = *(const uint4*)&QKV[(grow+r)*768 + c];
  }
  __syncthreads();
  const int h = tid>>5, q = (tid>>1)&15, eh = tid&1;
  const int eo = h*32 + eh*16;
  float qv[16];
  #pragma unroll
  for(int e2=0;e2<8;e2++){
    u32 x = *(const u32*)&sb[q*264 + eo + e2*2];
    qv[2*e2]=bfLO(x); qv[2*e2+1]=bfHI(x);
  }
  float sc[16];
  #pragma unroll
  for(int kk=0;kk<16;kk++){
    const u16* kr = &sb[4224 + kk*264 + eo];
    float s=0;
    #pragma unroll
    for(int e2=0;e2<8;e2++){
      u32 x = *(const u32*)&kr[e2*2];
      s = fmaf(qv[2*e2], bfLO(x), s);
      s = fmaf(qv[2*e2+1], bfHI(x), s);
    }
    s += __shfl_xor(s, 1);
    sc[kk] = s*0.17677669529663687f;
  }
  float m=sc[0];
  #pragma unroll
  for(int kk=1;kk<16;kk++) m=fmaxf(m,sc[kk]);
  float sum=0;
  #pragma unroll
  for(int kk=0;kk<16;kk++){ sc[kk]=expf(sc[kk]-m); sum+=sc[kk]; }
  float inv=1.0f/sum;
  float ov[16];
  #pragma unroll
  for(int e=0;e<16;e++) ov[e]=0.f;
  #pragma unroll
  for(int kk=0;kk<16;kk++){
    float p = sc[kk]*inv;
    const u16* vr = &sb[8448 + kk*264 + eo];
    #pragma unroll
    for(int e2=0;e2<8;e2++){
      u32 x = *(const u32*)&vr[e2*2];
      ov[2*e2]   = fmaf(p, bfLO(x), ov[2*e2]);
      ov[2*e2+1] = fmaf(p, bfHI(x), ov[2*e2+1]);
    }
  }
  u16* op = O + (grow+q)*256 + eo;
  #pragma unroll
  for(int b=0;b<4;b++){
    ushort4 t4; t4.x=f2bf(ov[4*b]); t4.y=f2bf(ov[4*b+1]); t4.z=f2bf(ov[4*b+2]); t4.w=f2bf(ov[4*b+3]);
    *(ushort4*)&op[b*4] = t4;
  }
}

// ---------- decoder cross-attention: bf16 LDS staging ----------
__global__ __launch_bounds__(256)
void attn_cross_kernel(const u16* __restrict__ Qc, const u16* __restrict__ KV,
                       u16* __restrict__ Oc, int loff){
  __shared__ float qs[256];
  __shared__ u16 kv[2][16*264];
  __shared__ float aw[128];
  const int t = threadIdx.x;
  const size_t g = blockIdx.x;
  qs[t] = bf2f(Qc[g*256+t]);
  #pragma unroll
  for(int it=0; it<4; it++){
    int e = (t + 256*it)*4;
    int r = e>>8, c = e&255;
    const u16* p = KV + (g*16+r)*1024 + loff + c;
    *(ushort4*)&kv[0][r*264 + c] = *(const ushort4*)p;        // K
    *(ushort4*)&kv[1][r*264 + c] = *(const ushort4*)(p+256);  // V
  }
  __syncthreads();
  if(t<128){
    int h=t>>4, j=t&15;
    const u16* kr = &kv[0][j*264 + h*32];
    const float* qq = &qs[h*32];
    float s=0;
    #pragma unroll
    for(int e2=0;e2<16;e2++){
      u32 x = *(const u32*)&kr[e2*2];
      s = fmaf(qq[2*e2],   bfLO(x), s);
      s = fmaf(qq[2*e2+1], bfHI(x), s);
    }
    aw[h*16+j] = s*0.17677669529663687f;
  }
  __syncthreads();
  if(t<8){
    float m=-1e30f;
    for(int j=0;j<16;j++) m=fmaxf(m, aw[t*16+j]);
    float sum=0;
    for(int j=0;j<16;j++){ float e=expf(aw[t*16+j]-m); aw[t*16+j]=e; sum+=e; }
    float inv=1.0f/sum;
    for(int j=0;j<16;j++) aw[t*16+j]*=inv;
  }
  __syncthreads();
  {
    int h=t>>5, e=t&31;
    float o=0;
    #pragma unroll
    for(int j=0;j<16;j++) o = fmaf(aw[h*16+j], bf2f(kv[1][j*264 + h*32 + e]), o);
    Oc[g*256+t] = f2bf(o);
  }
}

// ---------- final: out[g0+gl, :12] = tY[gl] @ W_gen (fp32 out) ----------
__global__ __launch_bounds__(64)
void final_kernel(const u16* __restrict__ TY, const float* __restrict__ Wg, float* __restrict__ out, int g0){
  __shared__ float y[256];
  const int lane = threadIdx.x;
  const size_t gl = blockIdx.x;
  ushort4 u = *(const ushort4*)(TY + gl*256 + (size_t)lane*4);
  y[lane*4+0]=bf2f(u.x); y[lane*4+1]=bf2f(u.y); y[lane*4+2]=bf2f(u.z); y[lane*4+3]=bf2f(u.w);
  __syncthreads();
  if(lane<12){
    float s=0;
    for(int d=0;d<256;d++) s = fmaf(y[d], Wg[d*12+lane], s);
    out[(g0+gl)*12+lane]=s;
  }
}

extern "C" void kernel_launch(void* const* d_in, const int* in_sizes, int n_in,
                              void* d_out, int out_size, void* d_ws, size_t ws_size,
                              hipStream_t stream)
{
  (void)in_sizes; (void)n_in; (void)out_size;
  const float* x_c  = (const float*)d_in[0];
  const float* A    = (const float*)d_in[1];
  const float* Wsrc = (const float*)d_in[2];
  const float* Wtgt = (const float*)d_in[3];
  const float* wsrc_f[7] = {(const float*)d_in[4],(const float*)d_in[5],(const float*)d_in[6],
                            (const float*)d_in[7],(const float*)d_in[8],(const float*)d_in[9],
                            (const float*)d_in[10]};
  const float* W_gen = (const float*)d_in[11];
  float* out = (float*)d_out;

  // ---- choose chunk size GC (groups per chunk) to fit ws_size ----
  auto align256 = [](size_t b)->size_t{ return (b + 255) & ~(size_t)255; };
  auto need_bytes = [&](int GC)->size_t{
    size_t b = 0;
    b += align256(512*16*4);
    for(int i=0;i<7;i++) b += align256((size_t)524288*2);
    b += align256((size_t)4*65536*2);        // wKV pack
    b += align256((size_t)2*65536*2)*2;      // wv_plain, wVO
    b += align256((size_t)GC*16*256*2)*2;    // cS, cY
    b += align256((size_t)GC*16*1024*2);     // big (QKV 768 / Tc 1024 / KVc 1024)
    b += align256((size_t)GC*256*2)*4;       // tgt, tY, tA, tO
    b += align256((size_t)GC*1024*2);        // tT
    return b;
  };
  int GC = 8192;
  while(GC > 128 && need_bytes(GC) > ws_size) GC >>= 1;

  // ---- workspace carve ----
  char* ws = (char*)d_ws;
  size_t off = 0;
  auto alloc = [&](size_t bytes)->char*{
    char* p = ws + off;
    off += (bytes + 255) & ~(size_t)255;
    return p;
  };
  int* idx = (int*)alloc(512*16*4);
  u16* wt[7];
  for(int i=0;i<7;i++) wt[i] = (u16*)alloc((size_t)524288*2);   // transposed bf16 weights
  u16* wKV      = (u16*)alloc((size_t)4*65536*2);  // [Wk0T|Wv0T|Wk1T|Wv1T] rows
  u16* wv_plain = (u16*)alloc((size_t)2*65536*2);  // dec_self Wv, plain bf16
  u16* wVO      = (u16*)alloc((size_t)2*65536*2);  // (Wv@Wo)^T per layer
  u16* cS  = (u16*)alloc((size_t)GC*16*256*2);
  u16* cY  = (u16*)alloc((size_t)GC*16*256*2);
  u16* big = (u16*)alloc((size_t)GC*16*1024*2);
  u16* tgt = (u16*)alloc((size_t)GC*256*2);
  u16* tY  = (u16*)alloc((size_t)GC*256*2);
  u16* tA  = (u16*)alloc((size_t)GC*256*2);
  u16* tO  = (u16*)alloc((size_t)GC*256*2);
  u16* tT  = (u16*)alloc((size_t)GC*1024*2);

  u16* wQKV = big;   // [Mr][768]  encoder attn phase
  u16* Tc   = big;   // [Mr][1024] encoder FFN phase
  u16* KVc  = big;   // [Mr][1024] decoder cross phase (both layers)

  // weights -> transposed bf16 (Bt[N][K]); all 7 tensors are 524288 elems
  {
    dim3 blk(32,8);
    tcvt_kernel<<<dim3( 256/32, 256/32, 8), blk, 0, stream>>>(wsrc_f[0], wt[0], 256, 256);
    tcvt_kernel<<<dim3(1024/32, 256/32, 2), blk, 0, stream>>>(wsrc_f[1], wt[1], 256,1024);
    tcvt_kernel<<<dim3( 256/32,1024/32, 2), blk, 0, stream>>>(wsrc_f[2], wt[2],1024, 256);
    tcvt_kernel<<<dim3( 256/32, 256/32, 8), blk, 0, stream>>>(wsrc_f[3], wt[3], 256, 256);
    tcvt_kernel<<<dim3( 256/32, 256/32, 8), blk, 0, stream>>>(wsrc_f[4], wt[4], 256, 256);
    tcvt_kernel<<<dim3(1024/32, 256/32, 2), blk, 0, stream>>>(wsrc_f[5], wt[5], 256,1024);
    tcvt_kernel<<<dim3( 256/32,1024/32, 2), blk, 0, stream>>>(wsrc_f[6], wt[6],1024, 256);
  }
  topk_kernel<<<512,64,0,stream>>>(A, idx);

  // pack cross-attn KV weights: rows [Wk0T | Wv0T | Wk1T | Wv1T]  (each slice 65536 u16)
  hipMemcpyAsync(wKV+0*65536, wt[4]+1*65536, 65536*2, hipMemcpyDeviceToDevice, stream);
  hipMemcpyAsync(wKV+1*65536, wt[4]+2*65536, 65536*2, hipMemcpyDeviceToDevice, stream);
  hipMemcpyAsync(wKV+2*65536, wt[4]+5*65536, 65536*2, hipMemcpyDeviceToDevice, stream);
  hipMemcpyAsync(wKV+3*65536, wt[4]+6*65536, 65536*2, hipMemcpyDeviceToDevice, stream);

  // precompute Wvo_t[l] = (Wv@Wo)^T for decoder self-attn (softmax over 1 key == identity)
  for(int l=0;l<2;l++){
    cvt_kernel<<<64,256,0,stream>>>(wsrc_f[3]+(size_t)(l*4+2)*65536, wv_plain+(size_t)l*65536, 16384);
    gemm_mfma<0><<<dim3(2,2),256,0,stream>>>(wt[3]+(size_t)(l*4+3)*65536, wv_plain+(size_t)l*65536,
                                             wVO+(size_t)l*65536, 256,256,256);
  }

  auto gemm = [&](const u16* Am, const u16* Bm, u16* Cm, int M_, int N_, int K_, int mode){
    dim3 grid(M_/128, N_/128);
    if(mode==1)      gemm_mfma<1><<<grid,256,0,stream>>>(Am,Bm,Cm,M_,N_,K_);
    else if(mode==2) gemm_mfma<2><<<grid,256,0,stream>>>(Am,Bm,Cm,M_,N_,K_);
    else             gemm_mfma<0><<<grid,256,0,stream>>>(Am,Bm,Cm,M_,N_,K_);
  };
  auto gemmw = [&](const u16* Am, const u16* Bm, u16* Cm, int M_, int N_, int K_, int mode){
    dim3 grid(M_/128, N_/256);
    if(mode==1) gemm_wide<1><<<grid,256,0,stream>>>(Am,Bm,Cm,M_,N_,K_);
    else        gemm_wide<0><<<grid,256,0,stream>>>(Am,Bm,Cm,M_,N_,K_);
  };
  auto gemm_ln = [&](const u16* Am, const u16* Bm, u16* Cm, u16* Ym, int M_, int K_){
    gemm_addln<<<dim3(M_/128),256,0,stream>>>(Am,Bm,Cm,Ym,M_,K_);
  };

  const int Mr = GC*16;   // encoder rows per chunk
  const int Md = GC;      // decoder rows per chunk

  for(int g0=0; g0<8192; g0+=GC){
    embed_kernel<<<GC,256,0,stream>>>(x_c, idx, Wsrc, Wtgt, cS, cY, tgt, tY, g0);

    // ---- encoder (L=2) ----
    for(int l=0;l<2;l++){
      const u16* Wat = wt[0] + (size_t)l*4*65536;
      gemmw(cY, Wat, wQKV, Mr, 768, 256, 0);           // Q|K|V packed (A = LN'd stream)
      attn_enc_kernel<<<GC,256,0,stream>>>(wQKV, cY);
      gemm_ln(cY, Wat+3*65536, cS, cY, Mr, 256);       // src += O@Wo ; cY = LN(src)
      gemmw(cY, wt[1]+(size_t)l*262144, Tc, Mr,1024, 256, 1);  // relu(y@F1)
      gemm_ln(Tc, wt[2]+(size_t)l*262144, cS, cY, Mr, 1024);   // src += t@F2 ; cY = LN(src)
    }
    // after layer 1, cY == LN(src) == memory
    gemmw(cY, wKV, KVc, Mr, 1024, 256, 0);             // K,V for BOTH decoder layers

    // ---- decoder (L=2) ----
    for(int l=0;l<2;l++){
      const u16* Wdc = wt[4] + (size_t)l*4*65536;
      // self-attn on 1 token: tgt += LN(tgt) @ (Wv@Wo) ; tY refreshed
      gemm_ln(tY, wVO+(size_t)l*65536, tgt, tY, Md, 256);
      // cross-attn
      gemm(tY, Wdc, tA, Md, 256, 256, 0);              // Qc
      attn_cross_kernel<<<GC,256,0,stream>>>(tA, KVc, tO, l*512);
      gemm_ln(tO, Wdc+3*65536, tgt, tY, Md, 256);      // tgt += attn@Wo ; tY = LN(tgt)
      // FFN
      gemmw(tY, wt[5]+(size_t)l*262144, tT, Md,1024, 256, 1);
      gemm_ln(tT, wt[6]+(size_t)l*262144, tgt, tY, Md, 1024);  // tgt += ; tY = LN(tgt)
    }

    final_kernel<<<GC,64,0,stream>>>(tY, W_gen, out, g0);
  }
}

// Round 15
// 1671.290 us; speedup vs baseline: 1.0874x; 1.0217x over previous
//
#include <hip/hip_runtime.h>

typedef unsigned short u16;
typedef unsigned int u32;
typedef __attribute__((ext_vector_type(8))) short short8;   // 8 bf16 (4 VGPRs)
typedef __attribute__((ext_vector_type(4))) float f32x4;    // MFMA acc

// ---------- bf16 helpers ----------
__device__ __forceinline__ float bf2f(unsigned v){ union{unsigned u; float f;} c; c.u = v<<16; return c.f; }
__device__ __forceinline__ u16 f2bf(float f){
  union{float f; unsigned u;} c; c.f=f;
  unsigned u = c.u;
  u += 0x7fffu + ((u>>16)&1u);
  return (u16)(u>>16);
}
__device__ __forceinline__ float bfLO(u32 x){ union{u32 u; float f;} c; c.u = x<<16;        return c.f; }
__device__ __forceinline__ float bfHI(u32 x){ union{u32 u; float f;} c; c.u = x&0xffff0000u; return c.f; }

#define GLDS(g, l) __builtin_amdgcn_global_load_lds( \
    (const __attribute__((address_space(1))) void*)(g), \
    (__attribute__((address_space(3))) void*)(l), 16, 0, 0)

// ---------- top-K=16 of each row of A (512x512), descending, stable ----------
__global__ void topk_kernel(const float* __restrict__ A, int* __restrict__ idx){
  __shared__ float vals[512];
  const int n = blockIdx.x, t = threadIdx.x; // 64 threads = 1 wave
  for(int i=t;i<512;i+=64) vals[i] = A[n*512+i];
  __syncthreads();
  for(int kk=0;kk<16;kk++){
    float bv = -1e30f; int bi = 1<<30;
    for(int i=t;i<512;i+=64){
      float v = vals[i];
      if(v > bv){ bv=v; bi=i; }
    }
    #pragma unroll
    for(int off=32; off>0; off>>=1){
      float ov = __shfl_down(bv, off);
      int   oi = __shfl_down(bi, off);
      if(ov > bv || (ov==bv && oi<bi)){ bv=ov; bi=oi; }
    }
    bi = __shfl(bi, 0);
    if(t==0){ idx[n*16+kk] = bi; vals[bi] = -1e30f; }
    __syncthreads();
  }
}

// ---------- ONE setup kernel: 7 transposes (f32->bf16), wKV pack, wv_plain convert ----------
// blocks 0..3583: transpose tiles (512 per tensor; 32x32 tile, 256 thr emulating (32,8))
// blocks 3584..3711: plain convert of dec_self Wv (2 layers) into wv_plain
__global__ __launch_bounds__(256)
void prep_kernel(const float* __restrict__ w0, const float* __restrict__ w1,
                 const float* __restrict__ w2, const float* __restrict__ w3,
                 const float* __restrict__ w4, const float* __restrict__ w5,
                 const float* __restrict__ w6,
                 u16* __restrict__ d0, u16* __restrict__ d1, u16* __restrict__ d2,
                 u16* __restrict__ d3, u16* __restrict__ d4, u16* __restrict__ d5,
                 u16* __restrict__ d6,
                 u16* __restrict__ wKV, u16* __restrict__ wv_plain){
  __shared__ float tbuf[32][33];
  const int b = blockIdx.x;
  if(b < 3584){
    const int t = b>>9, loc = b&511;
    const float* src; u16* dst; int R, C;
    switch(t){
      case 0: src=w0; dst=d0; R=256;  C=256;  break;
      case 1: src=w1; dst=d1; R=256;  C=1024; break;
      case 2: src=w2; dst=d2; R=1024; C=256;  break;
      case 3: src=w3; dst=d3; R=256;  C=256;  break;
      case 4: src=w4; dst=d4; R=256;  C=256;  break;
      case 5: src=w5; dst=d5; R=256;  C=1024; break;
      default:src=w6; dst=d6; R=1024; C=256;  break;
    }
    const int tilesx = C>>5, pm = tilesx*(R>>5);
    const int m = loc / pm, rem = loc - m*pm;
    const int ty_ = rem / tilesx, tx_ = rem - ty_*tilesx;
    const int c0 = tx_*32, r0 = ty_*32;
    src += (size_t)m*R*C;
    u16* dstm = dst + (size_t)m*R*C;
    const int tx = threadIdx.x & 31, ty = threadIdx.x >> 5;   // (32,8)
    #pragma unroll
    for(int i=0;i<4;i++) tbuf[ty*4+i][tx] = src[(size_t)(r0+ty*4+i)*C + c0+tx];
    __syncthreads();
    // wKV pack: dec_cross (t==4) mats {1,2,5,6} -> wKV slots {0,1,2,3} (same transposed layout)
    int slot = -1;
    if(t==4){
      if(m==1) slot=0; else if(m==2) slot=1; else if(m==5) slot=2; else if(m==6) slot=3;
    }
    #pragma unroll
    for(int i=0;i<4;i++){
      u16 v = f2bf(tbuf[tx][ty*4+i]);
      dstm[(size_t)(c0+ty*4+i)*R + r0+tx] = v;
      if(slot>=0) wKV[(size_t)slot*65536 + (c0+ty*4+i)*256 + r0+tx] = v;
    }
  } else {
    // plain convert: wv_plain[l] = bf16(w3 + (l*4+2)*65536), 16384 float4 per layer
    int idx4 = (b-3584)*256 + threadIdx.x;
    int l = (idx4 >= 16384) ? 1 : 0;
    int off4 = idx4 - l*16384;
    const float4 v = ((const float4*)(w3 + (size_t)(l*4+2)*65536))[off4];
    ushort4 o; o.x=f2bf(v.x); o.y=f2bf(v.y); o.z=f2bf(v.z); o.w=f2bf(v.w);
    ((ushort4*)(wv_plain + (size_t)l*65536))[off4] = o;
  }
}

// ---------- gather + embed + PE + fused LN: emits raw (S,TGT) and LN'd (SY,TGTY) ----------
__global__ __launch_bounds__(256)
void embed_kernel(const float* __restrict__ x_c, const int* __restrict__ idx,
                  const float* __restrict__ Wsrc, const float* __restrict__ Wtgt,
                  u16* __restrict__ S, u16* __restrict__ SY,
                  u16* __restrict__ TGT, u16* __restrict__ TGTY, int g0){
  __shared__ float xs[16][12];
  __shared__ float xt[12];
  __shared__ float sm[16][260];
  __shared__ float mv[16][2];
  __shared__ float wpart[4][2];
  __shared__ float tmv[2];
  const int gl = blockIdx.x, g = gl + g0, b = g>>9, n = g&511, d = threadIdx.x; // 256 thr
  const int w = d>>6, lane = d&63;
  if(d < 192){ int kk=d/12, t=d-kk*12; xs[kk][t] = x_c[(b*12+t)*512 + idx[n*16+kk]]; }
  else if(d < 204){ int t=d-192; xt[t] = x_c[(b*12+t)*512 + n]; }
  __syncthreads();
  float wsr[12], wtg[12];
  #pragma unroll
  for(int t=0;t<12;t++){ wsr[t]=Wsrc[t*256+d]; wtg[t]=Wtgt[t*256+d]; }
  const float freq = expf(-(float)(d & ~1) * (9.210340371976184f/256.0f));
  const bool odd = d & 1;
  float xv[16];
  #pragma unroll
  for(int kk=0;kk<16;kk++){
    float a=0;
    #pragma unroll
    for(int t=0;t<12;t++) a = fmaf(xs[kk][t], wsr[t], a);
    float pe = odd ? cosf(freq*(float)kk) : sinf(freq*(float)kk);
    xv[kk] = a*16.0f + pe;
    S[(size_t)(gl*16+kk)*256 + d] = f2bf(xv[kk]);
    sm[kk][d] = xv[kk];
  }
  float tv;
  {
    float a=0;
    #pragma unroll
    for(int t=0;t<12;t++) a = fmaf(xt[t], wtg[t], a);
    tv = a*16.0f + (odd?1.0f:0.0f);
    TGT[(size_t)gl*256 + d] = f2bf(tv);
  }
  {
    float s2=tv, q2=tv*tv;
    #pragma unroll
    for(int off=32; off>0; off>>=1){ s2+=__shfl_xor(s2,off); q2+=__shfl_xor(q2,off); }
    if(lane==0){ wpart[w][0]=s2; wpart[w][1]=q2; }
  }
  __syncthreads();
  {
    const int kk=d>>4, part=d&15;
    float s=0,q=0;
    #pragma unroll
    for(int t=0;t<16;t++){ float v=sm[kk][part*16+t]; s+=v; q+=v*v; }
    #pragma unroll
    for(int off=1; off<16; off<<=1){ s+=__shfl_xor(s,off); q+=__shfl_xor(q,off); }
    if(part==0){
      float mean=s*(1.0f/256.0f);
      float var=q*(1.0f/256.0f)-mean*mean;
      mv[kk][0]=mean; mv[kk][1]=rsqrtf(var+1e-6f);
    }
    if(d==0){
      float ts=wpart[0][0]+wpart[1][0]+wpart[2][0]+wpart[3][0];
      float tq=wpart[0][1]+wpart[1][1]+wpart[2][1]+wpart[3][1];
      float mean=ts*(1.0f/256.0f);
      float var=tq*(1.0f/256.0f)-mean*mean;
      tmv[0]=mean; tmv[1]=rsqrtf(var+1e-6f);
    }
  }
  __syncthreads();
  #pragma unroll
  for(int kk=0;kk<16;kk++)
    SY[(size_t)(gl*16+kk)*256 + d] = f2bf((xv[kk]-mv[kk][0])*mv[kk][1]);
  TGTY[(size_t)gl*256 + d] = f2bf((tv-tmv[0])*tmv[1]);
}

// ---------- MFMA GEMM: C[M,N] = A[M,K] @ B[K,N], Bt[N][K]. 128x128 tile. ----------
// MODE: 0 none, 1 relu, 2 add-residual.
template<int MODE>
__global__ __launch_bounds__(256)
void gemm_mfma(const u16* __restrict__ A, const u16* __restrict__ Bt, u16* __restrict__ C,
               int M, int N, int K)
{
  __shared__ u16 As[128*32];
  __shared__ u16 Bs[128*32];
  const int tid = threadIdx.x;
  const int w = tid>>6, l = tid&63;
  const int quad = l>>4, col16 = l&15;
  const int wr = (w>>1)*64, wc = (w&1)*64;
  const size_t m0 = (size_t)blockIdx.x*128;
  const size_t n0 = (size_t)blockIdx.y*128;

  const int sr = l>>2, sc = (l&3)*8;
  const int ca = w*2, cb = w*2+1;
  const u16* aG0 = A  + (m0 + ca*16 + sr)*K + sc;
  const u16* aG1 = A  + (m0 + cb*16 + sr)*K + sc;
  const u16* bG0 = Bt + (n0 + ca*16 + sr)*K + sc;
  const u16* bG1 = Bt + (n0 + cb*16 + sr)*K + sc;
  u16* aL0 = &As[ca*512];
  u16* aL1 = &As[cb*512];
  u16* bL0 = &Bs[ca*512];
  u16* bL1 = &Bs[cb*512];

  f32x4 acc[4][4];
  #pragma unroll
  for(int i=0;i<4;i++)
    #pragma unroll
    for(int j=0;j<4;j++) acc[i][j] = (f32x4){0.f,0.f,0.f,0.f};

  for(int k0=0;k0<K;k0+=32){
    GLDS(aG0 + k0, aL0);
    GLDS(aG1 + k0, aL1);
    GLDS(bG0 + k0, bL0);
    GLDS(bG1 + k0, bL1);
    __syncthreads();
    short8 af[4], bf[4];
    #pragma unroll
    for(int i=0;i<4;i++) af[i] = *(const short8*)&As[(wr + i*16 + col16)*32 + quad*8];
    #pragma unroll
    for(int j=0;j<4;j++) bf[j] = *(const short8*)&Bs[(wc + j*16 + col16)*32 + quad*8];
    #pragma unroll
    for(int i=0;i<4;i++)
      #pragma unroll
      for(int j=0;j<4;j++)
        acc[i][j] = __builtin_amdgcn_mfma_f32_16x16x32_bf16(af[i], bf[j], acc[i][j], 0,0,0);
    __syncthreads();
  }

  #pragma unroll
  for(int i=0;i<4;i++){
    #pragma unroll
    for(int r=0;r<4;r++){
      const size_t row = m0 + wr + i*16 + quad*4 + r;
      u16* cp = C + row*(size_t)N + n0 + wc + col16;
      #pragma unroll
      for(int j=0;j<4;j++){
        float v = acc[i][j][r];
        if(MODE==2) v += bf2f(cp[j*16]);
        if(MODE==1) v = fmaxf(v, 0.f);
        cp[j*16] = f2bf(v);
      }
    }
  }
}

// ---------- wide MFMA GEMM: 128x256 tile. grid (M/128, N/256). ----------
template<int MODE>
__global__ __launch_bounds__(256,2)
void gemm_wide(const u16* __restrict__ A, const u16* __restrict__ Bt, u16* __restrict__ C,
               int M, int N, int K)
{
  __shared__ u16 As[128*32];
  __shared__ u16 Bs[256*32];
  const int tid = threadIdx.x;
  const int w = tid>>6, l = tid&63;
  const int quad = l>>4, col16 = l&15;
  const int wr = (w>>1)*64, wc = (w&1)*128;
  const size_t m0 = (size_t)blockIdx.x*128;
  const size_t n0 = (size_t)blockIdx.y*256;

  const int sr = l>>2, sc = (l&3)*8;
  const u16* aG0 = A + (m0 + (w*2+0)*16 + sr)*K + sc;
  const u16* aG1 = A + (m0 + (w*2+1)*16 + sr)*K + sc;
  u16* aL0 = &As[(w*2+0)*512];
  u16* aL1 = &As[(w*2+1)*512];
  const u16* bG[4]; u16* bL[4];
  #pragma unroll
  for(int c=0;c<4;c++){
    int ch = w*4+c;
    bG[c] = Bt + (n0 + ch*16 + sr)*K + sc;
    bL[c] = &Bs[ch*512];
  }

  f32x4 acc[4][8];
  #pragma unroll
  for(int i=0;i<4;i++)
    #pragma unroll
    for(int j=0;j<8;j++) acc[i][j] = (f32x4){0.f,0.f,0.f,0.f};

  for(int k0=0;k0<K;k0+=32){
    GLDS(aG0 + k0, aL0);
    GLDS(aG1 + k0, aL1);
    #pragma unroll
    for(int c=0;c<4;c++) GLDS(bG[c] + k0, bL[c]);
    __syncthreads();
    short8 af[4], bf[8];
    #pragma unroll
    for(int i=0;i<4;i++) af[i] = *(const short8*)&As[(wr + i*16 + col16)*32 + quad*8];
    #pragma unroll
    for(int j=0;j<8;j++) bf[j] = *(const short8*)&Bs[(wc + j*16 + col16)*32 + quad*8];
    #pragma unroll
    for(int i=0;i<4;i++)
      #pragma unroll
      for(int j=0;j<8;j++)
        acc[i][j] = __builtin_amdgcn_mfma_f32_16x16x32_bf16(af[i], bf[j], acc[i][j], 0,0,0);
    __syncthreads();
  }

  #pragma unroll
  for(int i=0;i<4;i++){
    #pragma unroll
    for(int r=0;r<4;r++){
      const size_t row = m0 + wr + i*16 + quad*4 + r;
      u16* cp = C + row*(size_t)N + n0 + wc + col16;
      #pragma unroll
      for(int j=0;j<8;j++){
        float v = acc[i][j][r];
        if(MODE==1) v = fmaxf(v, 0.f);
        cp[j*16] = f2bf(v);
      }
    }
  }
}

// ---------- fused GEMM + residual-add + LayerNorm.  N fixed = 256. ----------
__global__ __launch_bounds__(256,2)
void gemm_addln(const u16* __restrict__ A, const u16* __restrict__ Bt,
                u16* __restrict__ C, u16* __restrict__ Y, int M, int K)
{
  __shared__ u16 As[128*32];
  __shared__ u16 Bs[256*32];
  __shared__ float ssum[128][2];
  __shared__ float ssq[128][2];
  const int tid = threadIdx.x;
  const int w = tid>>6, l = tid&63;
  const int quad = l>>4, col16 = l&15;
  const int wr = (w>>1)*64, wc = (w&1)*128;
  const int wh = w&1;
  const size_t m0 = (size_t)blockIdx.x*128;

  const int sr = l>>2, sc = (l&3)*8;
  const u16* aG0 = A + (m0 + (w*2+0)*16 + sr)*K + sc;
  const u16* aG1 = A + (m0 + (w*2+1)*16 + sr)*K + sc;
  u16* aL0 = &As[(w*2+0)*512];
  u16* aL1 = &As[(w*2+1)*512];
  const u16* bG[4]; u16* bL[4];
  #pragma unroll
  for(int c=0;c<4;c++){
    int ch = w*4+c;
    bG[c] = Bt + (size_t)(ch*16 + sr)*K + sc;
    bL[c] = &Bs[ch*512];
  }

  f32x4 acc[4][8];
  #pragma unroll
  for(int i=0;i<4;i++)
    #pragma unroll
    for(int j=0;j<8;j++) acc[i][j] = (f32x4){0.f,0.f,0.f,0.f};

  for(int k0=0;k0<K;k0+=32){
    GLDS(aG0 + k0, aL0);
    GLDS(aG1 + k0, aL1);
    #pragma unroll
    for(int c=0;c<4;c++) GLDS(bG[c] + k0, bL[c]);
    __syncthreads();
    short8 af[4], bf[8];
    #pragma unroll
    for(int i=0;i<4;i++) af[i] = *(const short8*)&As[(wr + i*16 + col16)*32 + quad*8];
    #pragma unroll
    for(int j=0;j<8;j++) bf[j] = *(const short8*)&Bs[(wc + j*16 + col16)*32 + quad*8];
    #pragma unroll
    for(int i=0;i<4;i++)
      #pragma unroll
      for(int j=0;j<8;j++)
        acc[i][j] = __builtin_amdgcn_mfma_f32_16x16x32_bf16(af[i], bf[j], acc[i][j], 0,0,0);
    __syncthreads();
  }

  #pragma unroll
  for(int i=0;i<4;i++){
    #pragma unroll
    for(int r=0;r<4;r++){
      const int lr = wr + i*16 + quad*4 + r;
      const u16* cp = C + (m0 + lr)*(size_t)256 + wc + col16;
      float s=0.f, q=0.f;
      #pragma unroll
      for(int j=0;j<8;j++){
        float v = acc[i][j][r] + bf2f(cp[j*16]);
        acc[i][j][r] = v;
        s += v; q += v*v;
      }
      #pragma unroll
      for(int off=1; off<16; off<<=1){ s+=__shfl_xor(s,off); q+=__shfl_xor(q,off); }
      if(col16==0){ ssum[lr][wh]=s; ssq[lr][wh]=q; }
    }
  }
  __syncthreads();
  #pragma unroll
  for(int i=0;i<4;i++){
    #pragma unroll
    for(int r=0;r<4;r++){
      const int lr = wr + i*16 + quad*4 + r;
      const float mean = (ssum[lr][0]+ssum[lr][1])*(1.0f/256.0f);
      const float var  = (ssq[lr][0]+ssq[lr][1])*(1.0f/256.0f) - mean*mean;
      const float rs   = rsqrtf(var + 1e-6f);
      u16* cp = C + (m0 + lr)*(size_t)256 + wc + col16;
      u16* yp = Y + (m0 + lr)*(size_t)256 + wc + col16;
      #pragma unroll
      for(int j=0;j<8;j++){
        float v = acc[i][j][r];
        cp[j*16] = f2bf(v);
        yp[j*16] = f2bf((v-mean)*rs);
      }
    }
  }
}

// ---------- encoder self-attention: QKV packed [M][768]; 1 group per 256-thr block ----------
__global__ __launch_bounds__(256)
void attn_enc_kernel(const u16* __restrict__ QKV, u16* __restrict__ O){
  __shared__ u16 sb[12672];
  const int tid = threadIdx.x;
  const size_t g = blockIdx.x;
  const size_t grow = g*16;
  #pragma unroll
  for(int it=0; it<6; it++){
    int e = (tid + 256*it)*8;
    int r = e/768, c = e - r*768;
    int t = c>>8, cc = c&255;
    *(uint4*)&sb[t*4224 + r*264 + cc] = *(const uint4*)&QKV[(grow+r)*768 + c];
  }
  __syncthreads();
  const int h = tid>>5, q = (tid>>1)&15, eh = tid&1;
  const int eo = h*32 + eh*16;
  float qv[16];
  #pragma unroll
  for(int e2=0;e2<8;e2++){
    u32 x = *(const u32*)&sb[q*264 + eo + e2*2];
    qv[2*e2]=bfLO(x); qv[2*e2+1]=bfHI(x);
  }
  float sc[16];
  #pragma unroll
  for(int kk=0;kk<16;kk++){
    const u16* kr = &sb[4224 + kk*264 + eo];
    float s=0;
    #pragma unroll
    for(int e2=0;e2<8;e2++){
      u32 x = *(const u32*)&kr[e2*2];
      s = fmaf(qv[2*e2], bfLO(x), s);
      s = fmaf(qv[2*e2+1], bfHI(x), s);
    }
    s += __shfl_xor(s, 1);
    sc[kk] = s*0.17677669529663687f;
  }
  float m=sc[0];
  #pragma unroll
  for(int kk=1;kk<16;kk++) m=fmaxf(m,sc[kk]);
  float sum=0;
  #pragma unroll
  for(int kk=0;kk<16;kk++){ sc[kk]=expf(sc[kk]-m); sum+=sc[kk]; }
  float inv=1.0f/sum;
  float ov[16];
  #pragma unroll
  for(int e=0;e<16;e++) ov[e]=0.f;
  #pragma unroll
  for(int kk=0;kk<16;kk++){
    float p = sc[kk]*inv;
    const u16* vr = &sb[8448 + kk*264 + eo];
    #pragma unroll
    for(int e2=0;e2<8;e2++){
      u32 x = *(const u32*)&vr[e2*2];
      ov[2*e2]   = fmaf(p, bfLO(x), ov[2*e2]);
      ov[2*e2+1] = fmaf(p, bfHI(x), ov[2*e2+1]);
    }
  }
  u16* op = O + (grow+q)*256 + eo;
  #pragma unroll
  for(int b=0;b<4;b++){
    ushort4 t4; t4.x=f2bf(ov[4*b]); t4.y=f2bf(ov[4*b+1]); t4.z=f2bf(ov[4*b+2]); t4.w=f2bf(ov[4*b+3]);
    *(ushort4*)&op[b*4] = t4;
  }
}

// ---------- decoder cross-attention: bf16 LDS staging ----------
__global__ __launch_bounds__(256)
void attn_cross_kernel(const u16* __restrict__ Qc, const u16* __restrict__ KV,
                       u16* __restrict__ Oc, int loff){
  __shared__ float qs[256];
  __shared__ u16 kv[2][16*264];
  __shared__ float aw[128];
  const int t = threadIdx.x;
  const size_t g = blockIdx.x;
  qs[t] = bf2f(Qc[g*256+t]);
  #pragma unroll
  for(int it=0; it<4; it++){
    int e = (t + 256*it)*4;
    int r = e>>8, c = e&255;
    const u16* p = KV + (g*16+r)*1024 + loff + c;
    *(ushort4*)&kv[0][r*264 + c] = *(const ushort4*)p;        // K
    *(ushort4*)&kv[1][r*264 + c] = *(const ushort4*)(p+256);  // V
  }
  __syncthreads();
  if(t<128){
    int h=t>>4, j=t&15;
    const u16* kr = &kv[0][j*264 + h*32];
    const float* qq = &qs[h*32];
    float s=0;
    #pragma unroll
    for(int e2=0;e2<16;e2++){
      u32 x = *(const u32*)&kr[e2*2];
      s = fmaf(qq[2*e2],   bfLO(x), s);
      s = fmaf(qq[2*e2+1], bfHI(x), s);
    }
    aw[h*16+j] = s*0.17677669529663687f;
  }
  __syncthreads();
  if(t<8){
    float m=-1e30f;
    for(int j=0;j<16;j++) m=fmaxf(m, aw[t*16+j]);
    float sum=0;
    for(int j=0;j<16;j++){ float e=expf(aw[t*16+j]-m); aw[t*16+j]=e; sum+=e; }
    float inv=1.0f/sum;
    for(int j=0;j<16;j++) aw[t*16+j]*=inv;
  }
  __syncthreads();
  {
    int h=t>>5, e=t&31;
    float o=0;
    #pragma unroll
    for(int j=0;j<16;j++) o = fmaf(aw[h*16+j], bf2f(kv[1][j*264 + h*32 + e]), o);
    Oc[g*256+t] = f2bf(o);
  }
}

// ---------- final: out[g0+gl, :12] = tY[gl] @ W_gen (fp32 out) ----------
__global__ __launch_bounds__(64)
void final_kernel(const u16* __restrict__ TY, const float* __restrict__ Wg, float* __restrict__ out, int g0){
  __shared__ float y[256];
  const int lane = threadIdx.x;
  const size_t gl = blockIdx.x;
  ushort4 u = *(const ushort4*)(TY + gl*256 + (size_t)lane*4);
  y[lane*4+0]=bf2f(u.x); y[lane*4+1]=bf2f(u.y); y[lane*4+2]=bf2f(u.z); y[lane*4+3]=bf2f(u.w);
  __syncthreads();
  if(lane<12){
    float s=0;
    for(int d=0;d<256;d++) s = fmaf(y[d], Wg[d*12+lane], s);
    out[(g0+gl)*12+lane]=s;
  }
}

extern "C" void kernel_launch(void* const* d_in, const int* in_sizes, int n_in,
                              void* d_out, int out_size, void* d_ws, size_t ws_size,
                              hipStream_t stream)
{
  (void)in_sizes; (void)n_in; (void)out_size;
  const float* x_c  = (const float*)d_in[0];
  const float* A    = (const float*)d_in[1];
  const float* Wsrc = (const float*)d_in[2];
  const float* Wtgt = (const float*)d_in[3];
  const float* wsrc_f[7] = {(const float*)d_in[4],(const float*)d_in[5],(const float*)d_in[6],
                            (const float*)d_in[7],(const float*)d_in[8],(const float*)d_in[9],
                            (const float*)d_in[10]};
  const float* W_gen = (const float*)d_in[11];
  float* out = (float*)d_out;

  // ---- choose chunk size GC (groups per chunk) to fit ws_size ----
  auto align256 = [](size_t b)->size_t{ return (b + 255) & ~(size_t)255; };
  auto need_bytes = [&](int GC)->size_t{
    size_t b = 0;
    b += align256(512*16*4);
    for(int i=0;i<7;i++) b += align256((size_t)524288*2);
    b += align256((size_t)4*65536*2);        // wKV pack
    b += align256((size_t)2*65536*2)*2;      // wv_plain, wVO
    b += align256((size_t)GC*16*256*2)*2;    // cS, cY
    b += align256((size_t)GC*16*1024*2);     // big (QKV 768 / Tc 1024 / KVc 1024)
    b += align256((size_t)GC*256*2)*4;       // tgt, tY, tA, tO
    b += align256((size_t)GC*1024*2);        // tT
    return b;
  };
  int GC = 8192;
  while(GC > 128 && need_bytes(GC) > ws_size) GC >>= 1;

  // ---- workspace carve ----
  char* ws = (char*)d_ws;
  size_t off = 0;
  auto alloc = [&](size_t bytes)->char*{
    char* p = ws + off;
    off += (bytes + 255) & ~(size_t)255;
    return p;
  };
  int* idx = (int*)alloc(512*16*4);
  u16* wt[7];
  for(int i=0;i<7;i++) wt[i] = (u16*)alloc((size_t)524288*2);   // transposed bf16 weights
  u16* wKV      = (u16*)alloc((size_t)4*65536*2);  // [Wk0T|Wv0T|Wk1T|Wv1T] rows
  u16* wv_plain = (u16*)alloc((size_t)2*65536*2);  // dec_self Wv, plain bf16
  u16* wVO      = (u16*)alloc((size_t)2*65536*2);  // (Wv@Wo)^T per layer
  u16* cS  = (u16*)alloc((size_t)GC*16*256*2);
  u16* cY  = (u16*)alloc((size_t)GC*16*256*2);
  u16* big = (u16*)alloc((size_t)GC*16*1024*2);
  u16* tgt = (u16*)alloc((size_t)GC*256*2);
  u16* tY  = (u16*)alloc((size_t)GC*256*2);
  u16* tA  = (u16*)alloc((size_t)GC*256*2);
  u16* tO  = (u16*)alloc((size_t)GC*256*2);
  u16* tT  = (u16*)alloc((size_t)GC*1024*2);

  u16* wQKV = big;   // [Mr][768]  encoder attn phase
  u16* Tc   = big;   // [Mr][1024] encoder FFN phase
  u16* KVc  = big;   // [Mr][1024] decoder cross phase (both layers)

  // ---- single fused setup: 7 transposed bf16 weights + wKV pack + wv_plain convert ----
  prep_kernel<<<3712,256,0,stream>>>(wsrc_f[0],wsrc_f[1],wsrc_f[2],wsrc_f[3],
                                     wsrc_f[4],wsrc_f[5],wsrc_f[6],
                                     wt[0],wt[1],wt[2],wt[3],wt[4],wt[5],wt[6],
                                     wKV, wv_plain);
  topk_kernel<<<512,64,0,stream>>>(A, idx);

  // precompute Wvo_t[l] = (Wv@Wo)^T for decoder self-attn (softmax over 1 key == identity)
  for(int l=0;l<2;l++){
    gemm_mfma<0><<<dim3(2,2),256,0,stream>>>(wt[3]+(size_t)(l*4+3)*65536, wv_plain+(size_t)l*65536,
                                             wVO+(size_t)l*65536, 256,256,256);
  }

  auto gemm = [&](const u16* Am, const u16* Bm, u16* Cm, int M_, int N_, int K_, int mode){
    dim3 grid(M_/128, N_/128);
    if(mode==1)      gemm_mfma<1><<<grid,256,0,stream>>>(Am,Bm,Cm,M_,N_,K_);
    else if(mode==2) gemm_mfma<2><<<grid,256,0,stream>>>(Am,Bm,Cm,M_,N_,K_);
    else             gemm_mfma<0><<<grid,256,0,stream>>>(Am,Bm,Cm,M_,N_,K_);
  };
  auto gemmw = [&](const u16* Am, const u16* Bm, u16* Cm, int M_, int N_, int K_, int mode){
    dim3 grid(M_/128, N_/256);
    if(mode==1) gemm_wide<1><<<grid,256,0,stream>>>(Am,Bm,Cm,M_,N_,K_);
    else        gemm_wide<0><<<grid,256,0,stream>>>(Am,Bm,Cm,M_,N_,K_);
  };
  auto gemm_ln = [&](const u16* Am, const u16* Bm, u16* Cm, u16* Ym, int M_, int K_){
    gemm_addln<<<dim3(M_/128),256,0,stream>>>(Am,Bm,Cm,Ym,M_,K_);
  };

  const int Mr = GC*16;   // encoder rows per chunk
  const int Md = GC;      // decoder rows per chunk

  for(int g0=0; g0<8192; g0+=GC){
    embed_kernel<<<GC,256,0,stream>>>(x_c, idx, Wsrc, Wtgt, cS, cY, tgt, tY, g0);

    // ---- encoder (L=2) ----
    for(int l=0;l<2;l++){
      const u16* Wat = wt[0] + (size_t)l*4*65536;
      gemmw(cY, Wat, wQKV, Mr, 768, 256, 0);           // Q|K|V packed (A = LN'd stream)
      attn_enc_kernel<<<GC,256,0,stream>>>(wQKV, cY);
      gemm_ln(cY, Wat+3*65536, cS, cY, Mr, 256);       // src += O@Wo ; cY = LN(src)
      gemmw(cY, wt[1]+(size_t)l*262144, Tc, Mr,1024, 256, 1);  // relu(y@F1)
      gemm_ln(Tc, wt[2]+(size_t)l*262144, cS, cY, Mr, 1024);   // src += t@F2 ; cY = LN(src)
    }
    // after layer 1, cY == LN(src) == memory
    gemmw(cY, wKV, KVc, Mr, 1024, 256, 0);             // K,V for BOTH decoder layers

    // ---- decoder (L=2) ----
    for(int l=0;l<2;l++){
      const u16* Wdc = wt[4] + (size_t)l*4*65536;
      // self-attn on 1 token: tgt += LN(tgt) @ (Wv@Wo) ; tY refreshed
      gemm_ln(tY, wVO+(size_t)l*65536, tgt, tY, Md, 256);
      // cross-attn
      gemm(tY, Wdc, tA, Md, 256, 256, 0);              // Qc
      attn_cross_kernel<<<GC,256,0,stream>>>(tA, KVc, tO, l*512);
      gemm_ln(tO, Wdc+3*65536, tgt, tY, Md, 256);      // tgt += attn@Wo ; tY = LN(tgt)
      // FFN
      gemmw(tY, wt[5]+(size_t)l*262144, tT, Md,1024, 256, 1);
      gemm_ln(tT, wt[6]+(size_t)l*262144, tgt, tY, Md, 1024);  // tgt += ; tY = LN(tgt)
    }

    final_kernel<<<GC,64,0,stream>>>(tY, W_gen, out, g0);
  }
}